// Round 8
// baseline (629.244 us; speedup 1.0000x reference)
//
#include <hip/hip_runtime.h>

typedef unsigned short u16;
typedef __bf16 bf16x8 __attribute__((ext_vector_type(8)));
typedef float f32x4 __attribute__((ext_vector_type(4)));

__device__ __forceinline__ u16 f2bf(float f) {
  unsigned int u = __builtin_bit_cast(unsigned int, f);
  u += 0x7fffu + ((u >> 16) & 1u);
  return (u16)(u >> 16);
}

// ===== Fragment-major (FM) layout for 16x16x32 bf16 MFMA operands =====
// chunk (ri=r>>4, ki=k>>5) is 64 lanes x 16B, contiguous 1KB:
//   lane = (r&15) | (((k>>3)&3)<<4),  byte = (k&7)*2
//   u16 addr(r,k) = ((ri*KC + ki)*512) + lane*8 + (k&7)      [KC = K/32]
// A wave's MFMA operand load is then ONE coalesced 16B/lane global load.

// ---------------- WT[j][c] = sum_s rmsw[s*1024+c] * Wdyn[(s*1024+c)*24 + j] ------------
__global__ __launch_bounds__(256) void weff_kernel(const float* __restrict__ rmsw,
                                                   const float* __restrict__ Wdyn,
                                                   float* __restrict__ WT) {
  int idx = blockIdx.x * 256 + threadIdx.x;  // 24576 threads
  int j = idx >> 10, c = idx & 1023;
  float s = 0.f;
#pragma unroll
  for (int st = 0; st < 4; ++st) {
    int r = st * 1024 + c;
    s += rmsw[r] * Wdyn[(long)r * 24 + j];
  }
  WT[idx] = s;
}

// ---------------- pack W (K x N fp32) -> FM bf16 of B^T (N rows, K cols) ----------------
// thread owns (n, k0..k0+7): 8 coalesced strided reads, ONE 16B FM write (full lane slot).
__global__ __launch_bounds__(256) void pack_weight(const float* __restrict__ W,
                                                   u16* __restrict__ FMB,
                                                   const int N, const int KC) {
  const long gid = (long)blockIdx.x * 256 + threadIdx.x;  // N*K/8 threads
  const int n = (int)(gid % N);
  const int k0 = (int)(gid / N) * 8;
  unsigned int p[4];
#pragma unroll
  for (int d = 0; d < 4; ++d) {
    const float lo = W[(long)(k0 + 2 * d) * N + n];
    const float hi = W[(long)(k0 + 2 * d + 1) * N + n];
    p[d] = (unsigned)f2bf(lo) | ((unsigned)f2bf(hi) << 16);
  }
  const long ad = ((long)(n >> 4) * KC + (k0 >> 5)) * 512 +
                  ((n & 15) + (((k0 >> 3) & 3) << 4)) * 8;
  *(uint4*)(FMB + ad) = make_uint4(p[0], p[1], p[2], p[3]);
}

// ---------------- per-token prep: rms, dynamic(24), gates, sinkhorn, preA(FM) -----------
__global__ __launch_bounds__(256) void prep_tokens(
    const float* __restrict__ x, const float* __restrict__ WT,
    const float* __restrict__ bias_pre, const float* __restrict__ bias_post,
    const float* __restrict__ bias_res, const float* __restrict__ a_pre,
    const float* __restrict__ a_post, const float* __restrict__ a_res,
    u16* __restrict__ preA, float* __restrict__ scal) {
  const int t = blockIdx.x;
  const int tid = threadIdx.x;
  const float4 xv = *(const float4*)(x + (long)t * 1024 + tid * 4);
  float ssq = xv.x * xv.x + xv.y * xv.y + xv.z * xv.z + xv.w * xv.w;
  float raw[24];
#pragma unroll
  for (int j = 0; j < 24; ++j) {
    const float4 w = *(const float4*)(WT + (long)j * 1024 + tid * 4);
    raw[j] = xv.x * w.x + xv.y * w.y + xv.z * w.z + xv.w * w.w;
  }
#pragma unroll
  for (int m = 1; m < 64; m <<= 1) {
    ssq += __shfl_xor(ssq, m);
#pragma unroll
    for (int j = 0; j < 24; ++j) raw[j] += __shfl_xor(raw[j], m);
  }
  __shared__ float red[4][25];
  __shared__ float tot[25];
  const int lane = tid & 63, wv = tid >> 6;
  if (lane == 0) {
#pragma unroll
    for (int j = 0; j < 24; ++j) red[wv][j] = raw[j];
    red[wv][24] = ssq;
  }
  __syncthreads();
  if (tid < 25) tot[tid] = red[0][tid] + red[1][tid] + red[2][tid] + red[3][tid];
  __syncthreads();

  const float rms = sqrtf(tot[24] * (1.0f / 1024.0f) + 1e-8f);
  const float rinv = 1.0f / rms;

  const float ap = a_pre[0];
  float s_pre = 0.f;
#pragma unroll
  for (int i = 0; i < 4; ++i)
    s_pre += 1.f / (1.f + expf(-(ap * tot[i] * rinv + bias_pre[i])));

  unsigned int lo = (unsigned)f2bf(s_pre * xv.x) | ((unsigned)f2bf(s_pre * xv.y) << 16);
  unsigned int hi = (unsigned)f2bf(s_pre * xv.z) | ((unsigned)f2bf(s_pre * xv.w) << 16);
  // FM write (KC=32 for GEMM1 A): m=t, k=c0..c0+3 (same 8-group since c0%4==0, c0%8 in {0,4})
  const int c0 = tid * 4;
  const long pa = ((long)(t >> 4) * 32 + (c0 >> 5)) * 512 +
                  ((t & 15) + (((c0 >> 3) & 3) << 4)) * 8 + (c0 & 7);
  *(uint2*)(preA + pa) = make_uint2(lo, hi);

  if (tid < 16) {
    const float ar = a_res[0];
    float Mv = expf(ar * tot[8 + tid] * rinv + bias_res[tid]);
#pragma unroll
    for (int it = 0; it < 20; ++it) {
      float cs = Mv + __shfl_xor(Mv, 4);
      cs += __shfl_xor(cs, 8);
      Mv = Mv / (cs + 1e-8f);   // col normalize (axis=-2)
      float rs = Mv + __shfl_xor(Mv, 1);
      rs += __shfl_xor(rs, 2);
      Mv = Mv / (rs + 1e-8f);   // row normalize (axis=-1)
    }
    float rs = Mv + __shfl_xor(Mv, 1);
    rs += __shfl_xor(rs, 2);
    if ((tid & 3) == 0) scal[(long)t * 8 + (tid >> 2)] = rs;  // r_i
  }
  if (tid < 4) {
    const float apo = a_post[0];
    float hp = 2.f / (1.f + expf(-(apo * tot[4 + tid] * rinv + bias_post[tid])));
    scal[(long)t * 8 + 4 + tid] = hp;  // H_post
  }
}

// ---------------- FM-direct bf16 MFMA GEMM: NO LDS, NO BARRIERS -------------------------
// Block 128x128, 4 waves (2x2), wave tile 64x64 = 4x4 of 16x16x32 MFMA.
// A, B both fragment-major. Per K-chunk: 8 coalesced 16B/lane global loads + 16 MFMA.
// Double-set register prefetch (compile-time indices). Sibling waves re-read the same
// 1KB frag lines -> L1/L2 hits. blockIdx.z*KC = split-K chunk offset.
// EPI: 0 = gelu -> bf16 FM dst (KCout chunks) | 3 = raw fp32 partial (ld N) + z*8192*1024
template <int EPI>
__global__ __launch_bounds__(256) void gemm_fm(const u16* __restrict__ A,
                                               const u16* __restrict__ B,
                                               const int KCtot, const int KC,
                                               const int N, const int KCout,
                                               const float* __restrict__ bias,
                                               void* __restrict__ dstv) {
  const int tid = threadIdx.x;
  const int lane = tid & 63;
  const int wave = tid >> 6;
  const int wm = wave >> 1, wn = wave & 1;
  const int kc0 = blockIdx.z * KC;

  const u16* Ab[4];
  const u16* Bb[4];
#pragma unroll
  for (int i = 0; i < 4; ++i) {
    Ab[i] = A + ((long)(blockIdx.y * 8 + wm * 4 + i) * KCtot + kc0) * 512 + lane * 8;
    Bb[i] = B + ((long)(blockIdx.x * 8 + wn * 4 + i) * KCtot + kc0) * 512 + lane * 8;
  }

  f32x4 acc[4][4] = {};
  bf16x8 a0[4], b0[4], a1[4], b1[4];
#pragma unroll
  for (int i = 0; i < 4; ++i) {
    a0[i] = *(const bf16x8*)(Ab[i]);
    b0[i] = *(const bf16x8*)(Bb[i]);
  }

  for (int kt = 0; kt < KC; kt += 2) {
    const long o1 = (long)(kt + 1) * 512;
#pragma unroll
    for (int i = 0; i < 4; ++i) {
      a1[i] = *(const bf16x8*)(Ab[i] + o1);
      b1[i] = *(const bf16x8*)(Bb[i] + o1);
    }
#pragma unroll
    for (int i = 0; i < 4; ++i)
#pragma unroll
      for (int j = 0; j < 4; ++j)
        acc[i][j] = __builtin_amdgcn_mfma_f32_16x16x32_bf16(a0[i], b0[j], acc[i][j], 0, 0, 0);
    if (kt + 2 < KC) {
      const long o2 = (long)(kt + 2) * 512;
#pragma unroll
      for (int i = 0; i < 4; ++i) {
        a0[i] = *(const bf16x8*)(Ab[i] + o2);
        b0[i] = *(const bf16x8*)(Bb[i] + o2);
      }
    }
#pragma unroll
    for (int i = 0; i < 4; ++i)
#pragma unroll
      for (int j = 0; j < 4; ++j)
        acc[i][j] = __builtin_amdgcn_mfma_f32_16x16x32_bf16(a1[i], b1[j], acc[i][j], 0, 0, 0);
  }

  // Epilogue. C/D layout: col = lane&15, row = (lane>>4)*4 + reg  [verified m89/m91]
  if constexpr (EPI == 0) {
    u16* dst = (u16*)dstv;  // FM layout with KCout chunks (h feeds GEMM2 as A)
#pragma unroll
    for (int i = 0; i < 4; ++i)
#pragma unroll
      for (int r = 0; r < 4; ++r) {
        const int row = blockIdx.y * 128 + wm * 64 + i * 16 + (lane >> 4) * 4 + r;
#pragma unroll
        for (int j = 0; j < 4; ++j) {
          const int col = blockIdx.x * 128 + wn * 64 + j * 16 + (lane & 15);
          float v = acc[i][j][r] + bias[col];
          float g = 0.5f * v * (1.0f + erff(v * 0.70710678118654752f));
          const long ad = ((long)(row >> 4) * KCout + (col >> 5)) * 512 +
                          ((row & 15) + (((col >> 3) & 3) << 4)) * 8 + (col & 7);
          dst[ad] = f2bf(g);
        }
      }
  } else {
    float* dst = (float*)dstv + (long)blockIdx.z * 8192 * 1024;
#pragma unroll
    for (int i = 0; i < 4; ++i)
#pragma unroll
      for (int r = 0; r < 4; ++r) {
        const long row = blockIdx.y * 128 + wm * 64 + i * 16 + (lane >> 4) * 4 + r;
#pragma unroll
        for (int j = 0; j < 4; ++j) {
          const long col = blockIdx.x * 128 + wn * 64 + j * 16 + (lane & 15);
          dst[row * N + col] = acc[i][j][r];
        }
      }
  }
}

// ---------------- combine2: merged(FM) = r_s*x + hp_s*(P0+P1+b2) ------------------------
__global__ __launch_bounds__(256) void combine2_kernel(const float* __restrict__ P,
                                                       const float* __restrict__ x,
                                                       const float* __restrict__ b2,
                                                       const float* __restrict__ scal,
                                                       u16* __restrict__ merged) {
  const long idx = (long)blockIdx.x * 256 + threadIdx.x;  // 8192*256
  const long t = idx >> 8;
  const int c = (int)(idx & 255) * 4;
  const float4 p0 = *(const float4*)(P + t * 1024 + c);
  const float4 p1 = *(const float4*)(P + 8192L * 1024 + t * 1024 + c);
  const float4 xv = *(const float4*)(x + t * 1024 + c);
  const float4 bv = *(const float4*)(b2 + c);
  const float f0 = p0.x + p1.x + bv.x, f1 = p0.y + p1.y + bv.y;
  const float f2 = p0.z + p1.z + bv.z, f3 = p0.w + p1.w + bv.w;
  const float4 rv = *(const float4*)(scal + t * 8);
  const float4 hv = *(const float4*)(scal + t * 8 + 4);
  const float rr[4] = {rv.x, rv.y, rv.z, rv.w};
  const float hh[4] = {hv.x, hv.y, hv.z, hv.w};
  // FM (KC=128 for GEMM3 A): m=t, k=s*1024+c
  const long base = ((long)(t >> 4) * 128 + (c >> 5)) * 512 +
                    ((t & 15) + (((c >> 3) & 3) << 4)) * 8 + (c & 7);
#pragma unroll
  for (int s = 0; s < 4; ++s) {
    unsigned int lo = (unsigned)f2bf(rr[s] * xv.x + hh[s] * f0) |
                      ((unsigned)f2bf(rr[s] * xv.y + hh[s] * f1) << 16);
    unsigned int hi = (unsigned)f2bf(rr[s] * xv.z + hh[s] * f2) |
                      ((unsigned)f2bf(rr[s] * xv.w + hh[s] * f3) << 16);
    *(uint2*)(merged + base + (long)s * 32 * 512) = make_uint2(lo, hi);
  }
}

// ---------------- combine3: out[t,c] = P0+P1+bout[c]+x[t,c] ----------------------------
__global__ __launch_bounds__(256) void combine3_kernel(const float* __restrict__ P,
                                                       const float* __restrict__ x,
                                                       const float* __restrict__ bout,
                                                       float* __restrict__ out) {
  const long idx = (long)blockIdx.x * 256 + threadIdx.x;
  const long t = idx >> 8;
  const int c = (int)(idx & 255) * 4;
  const float4 p0 = *(const float4*)(P + t * 1024 + c);
  const float4 p1 = *(const float4*)(P + 8192L * 1024 + t * 1024 + c);
  const float4 xv = *(const float4*)(x + t * 1024 + c);
  const float4 bv = *(const float4*)(bout + c);
  float4 o;
  o.x = p0.x + p1.x + bv.x + xv.x;
  o.y = p0.y + p1.y + bv.y + xv.y;
  o.z = p0.z + p1.z + bv.z + xv.z;
  o.w = p0.w + p1.w + bv.w + xv.w;
  *(float4*)(out + t * 1024 + c) = o;
}

extern "C" void kernel_launch(void* const* d_in, const int* in_sizes, int n_in,
                              void* d_out, int out_size, void* d_ws, size_t ws_size,
                              hipStream_t stream) {
  (void)in_sizes; (void)n_in; (void)out_size; (void)ws_size;
  const float* x = (const float*)d_in[0];
  const float* rmsw = (const float*)d_in[1];
  const float* Wdyn = (const float*)d_in[2];
  const float* bias_pre = (const float*)d_in[3];
  const float* bias_post = (const float*)d_in[4];
  const float* bias_res = (const float*)d_in[5];
  const float* a_pre = (const float*)d_in[6];
  const float* a_post = (const float*)d_in[7];
  const float* a_res = (const float*)d_in[8];
  const float* W1 = (const float*)d_in[9];
  const float* b1 = (const float*)d_in[10];
  const float* W2 = (const float*)d_in[11];
  const float* b2 = (const float*)d_in[12];
  const float* Wout = (const float*)d_in[13];
  const float* bout = (const float*)d_in[14];
  float* out = (float*)d_out;
  char* ws = (char*)d_ws;

  // ws layout (MiB):  [0,8) W1fm | [8,16) W2fm | [16,24) WOfm | [24,25) WT+scal
  //   [25,89)  h (bf16 FM) -> later ALIASED by merged (h dead after GEMM2)
  //   [89,153) P (2x 8192x1024 fp32) -> initially ALIASED by preA (dead after GEMM1)
  constexpr size_t MB = 1048576;
  u16* W1fm = (u16*)(ws);
  u16* W2fm = (u16*)(ws + 8 * MB);
  u16* WOfm = (u16*)(ws + 16 * MB);
  float* WT = (float*)(ws + 24 * MB);
  float* scal = (float*)(ws + 24 * MB + 98304);
  u16* h = (u16*)(ws + 25 * MB);
  u16* merged = (u16*)(ws + 25 * MB);   // aliases h
  float* P = (float*)(ws + 89 * MB);
  u16* preA = (u16*)(ws + 89 * MB);     // aliases P

  weff_kernel<<<96, 256, 0, stream>>>(rmsw, Wdyn, WT);
  pack_weight<<<2048, 256, 0, stream>>>(W1, W1fm, 4096, 32);    // K=1024 -> KC=32
  pack_weight<<<2048, 256, 0, stream>>>(W2, W2fm, 1024, 128);   // K=4096 -> KC=128
  pack_weight<<<2048, 256, 0, stream>>>(Wout, WOfm, 1024, 128);
  prep_tokens<<<8192, 256, 0, stream>>>(x, WT, bias_pre, bias_post, bias_res,
                                        a_pre, a_post, a_res, preA, scal);
  // GEMM1: h(FM,KCout=128) = gelu(preA @ W1 + b1)    M=8192 N=4096 K=1024
  gemm_fm<0><<<dim3(32, 64, 1), 256, 0, stream>>>(preA, W1fm, 32, 32, 4096, 128, b1, h);
  // GEMM2 (split-K x2): P[z] = h @ W2 partials       M=8192 N=1024 K=4096
  gemm_fm<3><<<dim3(8, 64, 2), 256, 0, stream>>>(h, W2fm, 128, 64, 1024, 0, nullptr, P);
  combine2_kernel<<<8192, 256, 0, stream>>>(P, x, b2, scal, merged);
  // GEMM3 (split-K x2): P[z] = merged @ Wout partials  M=8192 N=1024 K=4096
  gemm_fm<3><<<dim3(8, 64, 2), 256, 0, stream>>>(merged, WOfm, 128, 64, 1024, 0, nullptr, P);
  combine3_kernel<<<8192, 256, 0, stream>>>(P, x, bout, out);
}

// Round 9
// 545.529 us; speedup vs baseline: 1.1535x; 1.1535x over previous
//
#include <hip/hip_runtime.h>

typedef unsigned short u16;
typedef __bf16 bf16x8 __attribute__((ext_vector_type(8)));
typedef float f32x4 __attribute__((ext_vector_type(4)));

__device__ __forceinline__ u16 f2bf(float f) {
  unsigned int u = __builtin_bit_cast(unsigned int, f);
  u += 0x7fffu + ((u >> 16) & 1u);
  return (u16)(u >> 16);
}

// ===== Fragment-major (FM) layout for 16x16x32 bf16 MFMA operands =====
// chunk (ri=r>>4, ki=k>>5) is 64 lanes x 16B, contiguous 1KB:
//   lane = (r&15) | (((k>>3)&3)<<4),  byte = (k&7)*2
//   u16 addr(r,k) = ((ri*KC + ki)*512) + lane*8 + (k&7)      [KC = K/32]

// ---------------- WT[j][c] = sum_s rmsw[s*1024+c] * Wdyn[(s*1024+c)*24 + j] ------------
__global__ __launch_bounds__(256) void weff_kernel(const float* __restrict__ rmsw,
                                                   const float* __restrict__ Wdyn,
                                                   float* __restrict__ WT) {
  int idx = blockIdx.x * 256 + threadIdx.x;  // 24576 threads
  int j = idx >> 10, c = idx & 1023;
  float s = 0.f;
#pragma unroll
  for (int st = 0; st < 4; ++st) {
    int r = st * 1024 + c;
    s += rmsw[r] * Wdyn[(long)r * 24 + j];
  }
  WT[idx] = s;
}

// ---------------- pack W (K x N fp32) -> FM bf16 of B^T (N rows, K cols) ----------------
__global__ __launch_bounds__(256) void pack_weight(const float* __restrict__ W,
                                                   u16* __restrict__ FMB,
                                                   const int N, const int KC) {
  const long gid = (long)blockIdx.x * 256 + threadIdx.x;  // N*K/8 threads
  const int n = (int)(gid % N);
  const int k0 = (int)(gid / N) * 8;
  unsigned int p[4];
#pragma unroll
  for (int d = 0; d < 4; ++d) {
    const float lo = W[(long)(k0 + 2 * d) * N + n];
    const float hi = W[(long)(k0 + 2 * d + 1) * N + n];
    p[d] = (unsigned)f2bf(lo) | ((unsigned)f2bf(hi) << 16);
  }
  const long ad = ((long)(n >> 4) * KC + (k0 >> 5)) * 512 +
                  ((n & 15) + (((k0 >> 3) & 3) << 4)) * 8;
  *(uint4*)(FMB + ad) = make_uint4(p[0], p[1], p[2], p[3]);
}

// ---------------- per-token prep: rms, dynamic(24), gates, sinkhorn, preA(FM) -----------
__global__ __launch_bounds__(256) void prep_tokens(
    const float* __restrict__ x, const float* __restrict__ WT,
    const float* __restrict__ bias_pre, const float* __restrict__ bias_post,
    const float* __restrict__ bias_res, const float* __restrict__ a_pre,
    const float* __restrict__ a_post, const float* __restrict__ a_res,
    u16* __restrict__ preA, float* __restrict__ scal) {
  const int t = blockIdx.x;
  const int tid = threadIdx.x;
  const float4 xv = *(const float4*)(x + (long)t * 1024 + tid * 4);
  float ssq = xv.x * xv.x + xv.y * xv.y + xv.z * xv.z + xv.w * xv.w;
  float raw[24];
#pragma unroll
  for (int j = 0; j < 24; ++j) {
    const float4 w = *(const float4*)(WT + (long)j * 1024 + tid * 4);
    raw[j] = xv.x * w.x + xv.y * w.y + xv.z * w.z + xv.w * w.w;
  }
#pragma unroll
  for (int m = 1; m < 64; m <<= 1) {
    ssq += __shfl_xor(ssq, m);
#pragma unroll
    for (int j = 0; j < 24; ++j) raw[j] += __shfl_xor(raw[j], m);
  }
  __shared__ float red[4][25];
  __shared__ float tot[25];
  const int lane = tid & 63, wv = tid >> 6;
  if (lane == 0) {
#pragma unroll
    for (int j = 0; j < 24; ++j) red[wv][j] = raw[j];
    red[wv][24] = ssq;
  }
  __syncthreads();
  if (tid < 25) tot[tid] = red[0][tid] + red[1][tid] + red[2][tid] + red[3][tid];
  __syncthreads();

  const float rms = sqrtf(tot[24] * (1.0f / 1024.0f) + 1e-8f);
  const float rinv = 1.0f / rms;

  const float ap = a_pre[0];
  float s_pre = 0.f;
#pragma unroll
  for (int i = 0; i < 4; ++i)
    s_pre += 1.f / (1.f + expf(-(ap * tot[i] * rinv + bias_pre[i])));

  unsigned int lo = (unsigned)f2bf(s_pre * xv.x) | ((unsigned)f2bf(s_pre * xv.y) << 16);
  unsigned int hi = (unsigned)f2bf(s_pre * xv.z) | ((unsigned)f2bf(s_pre * xv.w) << 16);
  const int c0 = tid * 4;
  const long pa = ((long)(t >> 4) * 32 + (c0 >> 5)) * 512 +
                  ((t & 15) + (((c0 >> 3) & 3) << 4)) * 8 + (c0 & 7);
  *(uint2*)(preA + pa) = make_uint2(lo, hi);

  if (tid < 16) {
    const float ar = a_res[0];
    float Mv = expf(ar * tot[8 + tid] * rinv + bias_res[tid]);
#pragma unroll
    for (int it = 0; it < 20; ++it) {
      float cs = Mv + __shfl_xor(Mv, 4);
      cs += __shfl_xor(cs, 8);
      Mv = Mv / (cs + 1e-8f);   // col normalize (axis=-2)
      float rs = Mv + __shfl_xor(Mv, 1);
      rs += __shfl_xor(rs, 2);
      Mv = Mv / (rs + 1e-8f);   // row normalize (axis=-1)
    }
    float rs = Mv + __shfl_xor(Mv, 1);
    rs += __shfl_xor(rs, 2);
    if ((tid & 3) == 0) scal[(long)t * 8 + (tid >> 2)] = rs;  // r_i
  }
  if (tid < 4) {
    const float apo = a_post[0];
    float hp = 2.f / (1.f + expf(-(apo * tot[4 + tid] * rinv + bias_post[tid])));
    scal[(long)t * 8 + 4 + tid] = hp;  // H_post
  }
}

// ---------------- FM-direct bf16 MFMA GEMM: no LDS, no barriers, XCD-swizzled -----------
// Flat 1D grid of 64*GX blocks.  c = b&7 (assumed XCD via round-robin dispatch),
// x = (b>>3)%GX, y = c*8 + (b>>3)/GX  ->  all GX x-siblings of a y-tile are
// temporally-adjacent blocks on ONE XCD: A-tile hits that XCD's L2 after first use.
// Block 128x128, 4 waves (2x2), wave tile 64x64 = 4x4 of 16x16x32 MFMA.
// EPI: 0 = gelu -> bf16 FM dst (KCout)   [GEMM1 -> h]
//      1 = merged FM: r_s*x + hp_s*(f+bias)  [GEMM2, fused combine2]
//      2 = fp32 out = f + bias + x           [GEMM3, fused combine3]
template <int EPI>
__global__ __launch_bounds__(256) void gemm_fm(const u16* __restrict__ A,
                                               const u16* __restrict__ B,
                                               const int KCtot, const int GX,
                                               const int N, const int KCout,
                                               const float* __restrict__ bias,
                                               const float* __restrict__ X,
                                               const float* __restrict__ scal,
                                               void* __restrict__ dstv) {
  const int tid = threadIdx.x;
  const int lane = tid & 63;
  const int wave = tid >> 6;
  const int wm = wave >> 1, wn = wave & 1;
  const int b = blockIdx.x;
  const int c = b & 7;
  const int s = b >> 3;
  const int bx = s % GX;
  const int by = c * 8 + s / GX;

  const u16* Ab[4];
  const u16* Bb[4];
#pragma unroll
  for (int i = 0; i < 4; ++i) {
    Ab[i] = A + (long)(by * 8 + wm * 4 + i) * KCtot * 512 + lane * 8;
    Bb[i] = B + (long)(bx * 8 + wn * 4 + i) * KCtot * 512 + lane * 8;
  }

  f32x4 acc[4][4] = {};
  bf16x8 a0[4], b0[4], a1[4], b1[4];
#pragma unroll
  for (int i = 0; i < 4; ++i) {
    a0[i] = *(const bf16x8*)(Ab[i]);
    b0[i] = *(const bf16x8*)(Bb[i]);
  }

  for (int kt = 0; kt < KCtot; kt += 2) {
    const long o1 = (long)(kt + 1) * 512;
#pragma unroll
    for (int i = 0; i < 4; ++i) {
      a1[i] = *(const bf16x8*)(Ab[i] + o1);
      b1[i] = *(const bf16x8*)(Bb[i] + o1);
    }
#pragma unroll
    for (int i = 0; i < 4; ++i)
#pragma unroll
      for (int j = 0; j < 4; ++j)
        acc[i][j] = __builtin_amdgcn_mfma_f32_16x16x32_bf16(a0[i], b0[j], acc[i][j], 0, 0, 0);
    if (kt + 2 < KCtot) {
      const long o2 = (long)(kt + 2) * 512;
#pragma unroll
      for (int i = 0; i < 4; ++i) {
        a0[i] = *(const bf16x8*)(Ab[i] + o2);
        b0[i] = *(const bf16x8*)(Bb[i] + o2);
      }
    }
#pragma unroll
    for (int i = 0; i < 4; ++i)
#pragma unroll
      for (int j = 0; j < 4; ++j)
        acc[i][j] = __builtin_amdgcn_mfma_f32_16x16x32_bf16(a1[i], b1[j], acc[i][j], 0, 0, 0);
  }

  // Epilogue. C/D layout: col = lane&15, row = (lane>>4)*4 + reg  [verified m89/m91]
  if constexpr (EPI == 0) {
    u16* dst = (u16*)dstv;  // FM with KCout chunks (h feeds GEMM2 as A)
#pragma unroll
    for (int i = 0; i < 4; ++i)
#pragma unroll
      for (int r = 0; r < 4; ++r) {
        const int row = by * 128 + wm * 64 + i * 16 + (lane >> 4) * 4 + r;
#pragma unroll
        for (int j = 0; j < 4; ++j) {
          const int col = bx * 128 + wn * 64 + j * 16 + (lane & 15);
          float v = acc[i][j][r] + bias[col];
          float g = 0.5f * v * (1.0f + erff(v * 0.70710678118654752f));
          const long ad = ((long)(row >> 4) * KCout + (col >> 5)) * 512 +
                          ((row & 15) + (((col >> 3) & 3) << 4)) * 8 + (col & 7);
          dst[ad] = f2bf(g);
        }
      }
  } else if constexpr (EPI == 1) {
    u16* dst = (u16*)dstv;  // merged FM, KCout=128 chunks (k = s*1024 + col)
#pragma unroll
    for (int i = 0; i < 4; ++i)
#pragma unroll
      for (int r = 0; r < 4; ++r) {
        const int row = by * 128 + wm * 64 + i * 16 + (lane >> 4) * 4 + r;
        const float4 rv = *(const float4*)(scal + (long)row * 8);
        const float4 hv = *(const float4*)(scal + (long)row * 8 + 4);
        const float rr[4] = {rv.x, rv.y, rv.z, rv.w};
        const float hh[4] = {hv.x, hv.y, hv.z, hv.w};
#pragma unroll
        for (int j = 0; j < 4; ++j) {
          const int col = bx * 128 + wn * 64 + j * 16 + (lane & 15);
          const float f = acc[i][j][r] + bias[col];
          const float xval = X[(long)row * 1024 + col];
          const long base = ((long)(row >> 4) * 128 + (col >> 5)) * 512 +
                            ((row & 15) + (((col >> 3) & 3) << 4)) * 8 + (col & 7);
#pragma unroll
          for (int ss = 0; ss < 4; ++ss)
            dst[base + (long)ss * 32 * 512] = f2bf(rr[ss] * xval + hh[ss] * f);
        }
      }
  } else {
    float* dst = (float*)dstv;
#pragma unroll
    for (int i = 0; i < 4; ++i)
#pragma unroll
      for (int r = 0; r < 4; ++r) {
        const long row = by * 128 + wm * 64 + i * 16 + (lane >> 4) * 4 + r;
#pragma unroll
        for (int j = 0; j < 4; ++j) {
          const long col = bx * 128 + wn * 64 + j * 16 + (lane & 15);
          dst[row * 1024 + col] = acc[i][j][r] + bias[col] + X[row * 1024 + col];
        }
      }
  }
}

extern "C" void kernel_launch(void* const* d_in, const int* in_sizes, int n_in,
                              void* d_out, int out_size, void* d_ws, size_t ws_size,
                              hipStream_t stream) {
  (void)in_sizes; (void)n_in; (void)out_size; (void)ws_size;
  const float* x = (const float*)d_in[0];
  const float* rmsw = (const float*)d_in[1];
  const float* Wdyn = (const float*)d_in[2];
  const float* bias_pre = (const float*)d_in[3];
  const float* bias_post = (const float*)d_in[4];
  const float* bias_res = (const float*)d_in[5];
  const float* a_pre = (const float*)d_in[6];
  const float* a_post = (const float*)d_in[7];
  const float* a_res = (const float*)d_in[8];
  const float* W1 = (const float*)d_in[9];
  const float* b1 = (const float*)d_in[10];
  const float* W2 = (const float*)d_in[11];
  const float* b2 = (const float*)d_in[12];
  const float* Wout = (const float*)d_in[13];
  const float* bout = (const float*)d_in[14];
  float* out = (float*)d_out;
  char* ws = (char*)d_ws;

  // ws layout (MiB): [0,8) W1fm | [8,16) W2fm | [16,24) WOfm | [24,25) WT+scal
  //   [25,89)  h (bf16 FM, KCout=128)
  //   [89,153) merged (bf16 FM, KCout=128) -- initially ALIASED by preA (dead after GEMM1)
  constexpr size_t MB = 1048576;
  u16* W1fm = (u16*)(ws);
  u16* W2fm = (u16*)(ws + 8 * MB);
  u16* WOfm = (u16*)(ws + 16 * MB);
  float* WT = (float*)(ws + 24 * MB);
  float* scal = (float*)(ws + 24 * MB + 98304);
  u16* h = (u16*)(ws + 25 * MB);
  u16* merged = (u16*)(ws + 89 * MB);
  u16* preA = (u16*)(ws + 89 * MB);  // aliases merged (safe: preA dead before GEMM2)

  weff_kernel<<<96, 256, 0, stream>>>(rmsw, Wdyn, WT);
  pack_weight<<<2048, 256, 0, stream>>>(W1, W1fm, 4096, 32);    // K=1024 -> KC=32
  pack_weight<<<2048, 256, 0, stream>>>(W2, W2fm, 1024, 128);   // K=4096 -> KC=128
  pack_weight<<<2048, 256, 0, stream>>>(Wout, WOfm, 1024, 128);
  prep_tokens<<<8192, 256, 0, stream>>>(x, WT, bias_pre, bias_post, bias_res,
                                        a_pre, a_post, a_res, preA, scal);
  // GEMM1: h(FM) = gelu(preA @ W1 + b1)   M=8192 N=4096 K=1024; grid 8*8*GX, GX=32
  gemm_fm<0><<<2048, 256, 0, stream>>>(preA, W1fm, 32, 32, 4096, 128, b1, nullptr, nullptr, h);
  // GEMM2: merged(FM) = r*x + hp*(h @ W2 + b2)   M=8192 N=1024 K=4096; GX=8
  gemm_fm<1><<<512, 256, 0, stream>>>(h, W2fm, 128, 8, 1024, 128, b2, x, scal, merged);
  // GEMM3: out = merged @ Wout + bout + x        M=8192 N=1024 K=4096; GX=8
  gemm_fm<2><<<512, 256, 0, stream>>>(merged, WOfm, 128, 8, 1024, 0, bout, x, nullptr, out);
}